// Round 1
// baseline (5260.649 us; speedup 1.0000x reference)
//
#include <hip/hip_runtime.h>
#include <math.h>

#define B_TOK  16384
#define FEAT   8
#define EMB    128
#define DMODEL 1024
#define DHALF  512
#define NWIDE  64
#define VOCAB  100000
#define NEXP   16
#define CAP    4096
#define D3     3072

__device__ __forceinline__ float leaky(float x){ return x >= 0.f ? x : 0.2f * x; }

// ---------------------------------------------------------------------------
// Embedding gather: emb[b, f*128+d] = tab[f, deep_in[b,f], d]
// ---------------------------------------------------------------------------
__global__ __launch_bounds__(256) void k_emb(const int* __restrict__ deep_in,
                                             const float* __restrict__ tab,
                                             float* __restrict__ emb){
    int b = blockIdx.x, tid = threadIdx.x;
    int idx = tid * 4;             // 0..1023, 4 floats per thread
    int f = idx >> 7, d = idx & 127;
    int id = deep_in[b * FEAT + f];
    float4 v = *(const float4*)(tab + ((size_t)f * VOCAB + (size_t)id) * EMB + d);
    *(float4*)(emb + (size_t)b * DMODEL + idx) = v;
}

// ---------------------------------------------------------------------------
// Generic fp32 tiled GEMM: C[M,N] = act(A[M,K] @ B[K,N] + bias), 64x64 tile,
// BK=16, 256 threads, 4x4 micro-tile. ACT: 0=none, 1=leaky.
// ---------------------------------------------------------------------------
template<int ACT>
__global__ __launch_bounds__(256) void gemm_plain(const float* __restrict__ A,
                                                  const float* __restrict__ Bm,
                                                  const float* __restrict__ bias,
                                                  float* __restrict__ C,
                                                  int K, int lda, int ldb, int ldc){
    __shared__ float As[16][68];
    __shared__ float Bs[16][68];
    int tid = threadIdx.x;
    int m0 = blockIdx.y * 64, n0 = blockIdx.x * 64;
    int arow = tid >> 2, ak = (tid & 3) << 2;        // A: row, k-quad
    int bcol = tid & 63, bk0 = (tid >> 6) << 2;      // B: col, k-quad base
    const float* aptr = A + (size_t)(m0 + arow) * lda + ak;
    const float* bptr = Bm + (size_t)bk0 * ldb + n0 + bcol;
    int tr = (tid >> 4) << 2, tc = (tid & 15) << 2;
    float acc[4][4] = {};
    for (int k0 = 0; k0 < K; k0 += 16){
        float4 av = *(const float4*)(aptr + k0);
        As[ak + 0][arow] = av.x; As[ak + 1][arow] = av.y;
        As[ak + 2][arow] = av.z; As[ak + 3][arow] = av.w;
        #pragma unroll
        for (int j = 0; j < 4; j++)
            Bs[bk0 + j][bcol] = bptr[(size_t)(k0 + j) * ldb];
        __syncthreads();
        #pragma unroll
        for (int kk = 0; kk < 16; kk++){
            float a[4], b[4];
            *(float4*)a = *(const float4*)&As[kk][tr];
            *(float4*)b = *(const float4*)&Bs[kk][tc];
            #pragma unroll
            for (int i = 0; i < 4; i++)
                #pragma unroll
                for (int j = 0; j < 4; j++)
                    acc[i][j] += a[i] * b[j];
        }
        __syncthreads();
    }
    #pragma unroll
    for (int i = 0; i < 4; i++){
        int m = m0 + tr + i;
        #pragma unroll
        for (int j = 0; j < 4; j++){
            int n = n0 + tc + j;
            float v = acc[i][j] + bias[n];
            if (ACT == 1) v = leaky(v);
            C[(size_t)m * ldc + n] = v;
        }
    }
}

// ---------------------------------------------------------------------------
// Wide head: ctx[b, 512+j] = leaky(gamma[j]*(x@W + b)[j]*invs + beta[j])
// ---------------------------------------------------------------------------
__global__ __launch_bounds__(256) void k_wide(const float* __restrict__ win,
                                              const float* __restrict__ wW,
                                              const float* __restrict__ wb,
                                              const float* __restrict__ gamma,
                                              const float* __restrict__ beta,
                                              float* __restrict__ ctx){
    int b = blockIdx.x, tid = threadIdx.x;
    __shared__ float xs[NWIDE];
    if (tid < NWIDE) xs[tid] = win[b * NWIDE + tid];
    __syncthreads();
    const float invs = 0.99999500003749969f;   // 1/sqrt(1+1e-5)
    float acc0 = 0.f, acc1 = 0.f;
    #pragma unroll 8
    for (int k = 0; k < NWIDE; k++){
        float xv = xs[k];
        acc0 += xv * wW[k * DHALF + tid];
        acc1 += xv * wW[k * DHALF + tid + 256];
    }
    int j0 = tid, j1 = tid + 256;
    float v0 = gamma[j0] * ((acc0 + wb[j0]) * invs) + beta[j0];
    float v1 = gamma[j1] * ((acc1 + wb[j1]) * invs) + beta[j1];
    ctx[(size_t)b * DMODEL + DHALF + j0] = leaky(v0);
    ctx[(size_t)b * DMODEL + DHALF + j1] = leaky(v1);
}

// ---------------------------------------------------------------------------
// Router: one wave per token. logits = x @ rW, softmax, top-2 (lowest-index
// tiebreak, matching lax.top_k), per-block partial prob sums for aux.
// ---------------------------------------------------------------------------
__global__ __launch_bounds__(256) void k_router(const float* __restrict__ ctx,
                                                const float* __restrict__ rW,
                                                int* __restrict__ e1, int* __restrict__ e2,
                                                float* __restrict__ w1, float* __restrict__ w2,
                                                float* __restrict__ psum_part){
    int tid = threadIdx.x;
    int wave = tid >> 6, lane = tid & 63;
    int t = blockIdx.x * 4 + wave;
    __shared__ float ps[NEXP];
    if (tid < NEXP) ps[tid] = 0.f;
    __syncthreads();
    float acc[NEXP];
    #pragma unroll
    for (int e = 0; e < NEXP; e++) acc[e] = 0.f;
    const float* x = ctx + (size_t)t * DMODEL;
    for (int k = lane; k < DMODEL; k += 64){
        float xv = x[k];
        const float* wr = rW + k * NEXP;
        #pragma unroll
        for (int e = 0; e < NEXP; e++) acc[e] += xv * wr[e];
    }
    #pragma unroll
    for (int off = 32; off; off >>= 1)
        #pragma unroll
        for (int e = 0; e < NEXP; e++) acc[e] += __shfl_xor(acc[e], off, 64);
    // softmax (all lanes redundantly)
    float m = acc[0];
    #pragma unroll
    for (int e = 1; e < NEXP; e++) m = fmaxf(m, acc[e]);
    float p[NEXP], s = 0.f;
    #pragma unroll
    for (int e = 0; e < NEXP; e++){ p[e] = expf(acc[e] - m); s += p[e]; }
    float inv = 1.f / s;
    #pragma unroll
    for (int e = 0; e < NEXP; e++) p[e] *= inv;
    int b1 = 0; float v1 = p[0];
    #pragma unroll
    for (int e = 1; e < NEXP; e++) if (p[e] > v1){ v1 = p[e]; b1 = e; }
    int b2 = (b1 == 0) ? 1 : 0; float v2 = p[b2];
    #pragma unroll
    for (int e = 0; e < NEXP; e++) if (e != b1 && p[e] > v2){ v2 = p[e]; b2 = e; }
    if (lane == 0){
        e1[t] = b1; e2[t] = b2; w1[t] = v1; w2[t] = v2;
        #pragma unroll
        for (int e = 0; e < NEXP; e++) atomicAdd(&ps[e], p[e]);
    }
    __syncthreads();
    if (tid < NEXP) psum_part[blockIdx.x * NEXP + tid] = ps[tid];
}

__global__ __launch_bounds__(256) void k_psum_reduce(const float* __restrict__ part,
                                                     float* __restrict__ psum){
    int e = blockIdx.x, tid = threadIdx.x;
    float s = 0.f;
    for (int b = tid; b < B_TOK / 4; b += 256) s += part[b * NEXP + e];
    #pragma unroll
    for (int off = 32; off; off >>= 1) s += __shfl_down(s, off, 64);
    __shared__ float red[4];
    int wave = tid >> 6, lane = tid & 63;
    if (lane == 0) red[wave] = s;
    __syncthreads();
    if (tid == 0) psum[e] = red[0] + red[1] + red[2] + red[3];
}

// ---------------------------------------------------------------------------
// Exact-order capacity assignment: blocked histogram -> scan -> serial assign
// ---------------------------------------------------------------------------
__global__ __launch_bounds__(256) void k_hist(const int* __restrict__ e1, const int* __restrict__ e2,
                                              int* __restrict__ bh1, int* __restrict__ bh2){
    __shared__ int h1[NEXP], h2[NEXP];
    int tid = threadIdx.x;
    if (tid < NEXP){ h1[tid] = 0; h2[tid] = 0; }
    __syncthreads();
    int t = blockIdx.x * 256 + tid;
    atomicAdd(&h1[e1[t]], 1);
    atomicAdd(&h2[e2[t]], 1);
    __syncthreads();
    if (tid < NEXP){ bh1[blockIdx.x * NEXP + tid] = h1[tid]; bh2[blockIdx.x * NEXP + tid] = h2[tid]; }
}

__global__ __launch_bounds__(64) void k_scan(const int* __restrict__ bh1, const int* __restrict__ bh2,
                                             int* __restrict__ offs1, int* __restrict__ offs2,
                                             int* __restrict__ raw_total, int* __restrict__ ne,
                                             int* __restrict__ row_base){
    int e = threadIdx.x;
    if (e < NEXP){
        int run = 0;
        for (int b = 0; b < 64; b++){ offs1[b * NEXP + e] = run; run += bh1[b * NEXP + e]; }
        int run2 = run;                    // slot-1 positions start after all slot-0
        for (int b = 0; b < 64; b++){ offs2[b * NEXP + e] = run2; run2 += bh2[b * NEXP + e]; }
        raw_total[e] = run2;
        ne[e] = run2 < CAP ? run2 : CAP;
    }
    __syncthreads();
    if (e == 0){
        int rb = 0;
        for (int x = 0; x < NEXP; x++){ row_base[x] = rb; rb += ne[x]; }
        row_base[NEXP] = rb;
    }
}

__global__ __launch_bounds__(64) void k_assign(const int* __restrict__ e1, const int* __restrict__ e2,
                                               const int* __restrict__ offs1, const int* __restrict__ offs2,
                                               int* __restrict__ expert_rows, int* __restrict__ keep){
    __shared__ int run[NEXP];
    int blk = blockIdx.x, slot = blockIdx.y;
    const int* offs = slot ? offs2 : offs1;
    if (threadIdx.x < NEXP) run[threadIdx.x] = offs[blk * NEXP + threadIdx.x];
    __syncthreads();
    if (threadIdx.x != 0) return;
    const int* ee = slot ? e2 : e1;
    for (int i = 0; i < 256; i++){
        int t = blk * 256 + i;
        int e = ee[t];
        int p = run[e]++;
        if (p < CAP){
            expert_rows[e * CAP + p] = t | (slot << 16);
            keep[slot * B_TOK + t] = 1;
        } else {
            keep[slot * B_TOK + t] = 0;
        }
    }
}

// ---------------------------------------------------------------------------
// Grouped expert GEMM. LAYER 1: h[row_base[e]+r] = leaky(ctx[tok] @ W1[e] + b1[e])
//                      LAYER 2: y[slot*B+tok]    =       h[...] @ W2[e] + b2[e]
// grid = (N/64, CAP/64, NEXP); tiles beyond ne[e] early-exit.
// ---------------------------------------------------------------------------
template<int LAYER>
__global__ __launch_bounds__(256) void gemm_expert(const float* __restrict__ ctx,
                                                   const float* __restrict__ h_in,
                                                   const float* __restrict__ Wall,
                                                   const float* __restrict__ ball,
                                                   float* __restrict__ h_out,
                                                   float* __restrict__ y_buf,
                                                   const int* __restrict__ expert_rows,
                                                   const int* __restrict__ ne_arr,
                                                   const int* __restrict__ row_base){
    int e = blockIdx.z;
    int ne = ne_arr[e];
    int m0 = blockIdx.y * 64;
    if (m0 >= ne) return;
    int n0 = blockIdx.x * 64;
    const float* Bm   = Wall + (size_t)e * DMODEL * DMODEL;
    const float* bias = ball + e * DMODEL;
    int rb = row_base[e];
    __shared__ float As[16][68];
    __shared__ float Bs[16][68];
    __shared__ int   recs[64];
    int tid = threadIdx.x;
    if (tid < 64){
        int r = m0 + tid;
        recs[tid] = (r < ne) ? expert_rows[e * CAP + r] : 0;
    }
    __syncthreads();
    int arow = tid >> 2, ak = (tid & 3) << 2;
    int bcol = tid & 63, bk0 = (tid >> 6) << 2;
    const float* aptr;
    if (LAYER == 1){
        int tok = recs[arow] & 0xFFFF;
        aptr = ctx + (size_t)tok * DMODEL + ak;
    } else {
        int r = m0 + arow; if (r >= ne) r = ne - 1;
        aptr = h_in + (size_t)(rb + r) * DMODEL + ak;
    }
    const float* bptr = Bm + (size_t)bk0 * DMODEL + n0 + bcol;
    int tr = (tid >> 4) << 2, tc = (tid & 15) << 2;
    float acc[4][4] = {};
    for (int k0 = 0; k0 < DMODEL; k0 += 16){
        float4 av = *(const float4*)(aptr + k0);
        As[ak + 0][arow] = av.x; As[ak + 1][arow] = av.y;
        As[ak + 2][arow] = av.z; As[ak + 3][arow] = av.w;
        #pragma unroll
        for (int j = 0; j < 4; j++)
            Bs[bk0 + j][bcol] = bptr[(size_t)(k0 + j) * DMODEL];
        __syncthreads();
        #pragma unroll
        for (int kk = 0; kk < 16; kk++){
            float a[4], b[4];
            *(float4*)a = *(const float4*)&As[kk][tr];
            *(float4*)b = *(const float4*)&Bs[kk][tc];
            #pragma unroll
            for (int i = 0; i < 4; i++)
                #pragma unroll
                for (int j = 0; j < 4; j++)
                    acc[i][j] += a[i] * b[j];
        }
        __syncthreads();
    }
    #pragma unroll
    for (int i = 0; i < 4; i++){
        int r = m0 + tr + i;
        if (r >= ne) continue;
        int rec = recs[tr + i];
        #pragma unroll
        for (int j = 0; j < 4; j++){
            int n = n0 + tc + j;
            float v = acc[i][j] + bias[n];
            if (LAYER == 1){
                h_out[(size_t)(rb + r) * DMODEL + n] = leaky(v);
            } else {
                int tok = rec & 0xFFFF, slot = rec >> 16;
                y_buf[((size_t)slot * B_TOK + tok) * DMODEL + n] = v;
            }
        }
    }
}

// ---------------------------------------------------------------------------
// Combine: moe[t] = keep0*w1*y0[t] + keep1*w2*y1[t]
// ---------------------------------------------------------------------------
__global__ __launch_bounds__(256) void k_combine(const float* __restrict__ y_buf,
                                                 const int* __restrict__ keep,
                                                 const float* __restrict__ w1,
                                                 const float* __restrict__ w2,
                                                 float* __restrict__ moe){
    int t = blockIdx.x, tid = threadIdx.x;
    float a = keep[t] ? w1[t] : 0.f;
    float b = keep[B_TOK + t] ? w2[t] : 0.f;
    size_t o = (size_t)t * DMODEL + tid * 4;
    float4 y0 = *(const float4*)(y_buf + o);
    float4 y1 = *(const float4*)(y_buf + (size_t)B_TOK * DMODEL + o);
    float4 r;
    r.x = a * y0.x + b * y1.x;
    r.y = a * y0.y + b * y1.y;
    r.z = a * y0.z + b * y1.z;
    r.w = a * y0.w + b * y1.w;
    *(float4*)(moe + o) = r;
}

// ---------------------------------------------------------------------------
// Output head: sigmoid(m1[t] . out_W + out_b)
// ---------------------------------------------------------------------------
__global__ __launch_bounds__(256) void k_out(const float* __restrict__ m1,
                                             const float* __restrict__ oW,
                                             const float* __restrict__ ob,
                                             float* __restrict__ out){
    int t = blockIdx.x, tid = threadIdx.x;
    float4 x = *(const float4*)(m1 + (size_t)t * DMODEL + tid * 4);
    float4 w = *(const float4*)(oW + tid * 4);
    float s = x.x * w.x + x.y * w.y + x.z * w.z + x.w * w.w;
    #pragma unroll
    for (int off = 32; off; off >>= 1) s += __shfl_down(s, off, 64);
    __shared__ float red[4];
    int wave = tid >> 6, lane = tid & 63;
    if (lane == 0) red[wave] = s;
    __syncthreads();
    if (tid == 0){
        float tot = red[0] + red[1] + red[2] + red[3] + ob[0];
        out[t] = 1.f / (1.f + expf(-tot));
    }
}

__global__ void k_aux(const int* __restrict__ raw_total, const float* __restrict__ psum,
                      float* __restrict__ out){
    if (threadIdx.x == 0 && blockIdx.x == 0){
        float a = 0.f;
        for (int e = 0; e < NEXP; e++)
            a += ((float)raw_total[e] / (2.0f * B_TOK)) * (psum[e] / (float)B_TOK);
        out[B_TOK] = (float)NEXP * a;
    }
}

// ---------------------------------------------------------------------------
extern "C" void kernel_launch(void* const* d_in, const int* in_sizes, int n_in,
                              void* d_out, int out_size, void* d_ws, size_t ws_size,
                              hipStream_t stream){
    const int*   deep_in = (const int*)  d_in[0];
    const float* wide_in = (const float*)d_in[1];
    const float* tab     = (const float*)d_in[2];
    const float* deep_W  = (const float*)d_in[3];
    const float* deep_b  = (const float*)d_in[4];
    const float* wide_W  = (const float*)d_in[5];
    const float* wide_b  = (const float*)d_in[6];
    const float* gamma   = (const float*)d_in[7];
    const float* beta    = (const float*)d_in[8];
    const float* rW      = (const float*)d_in[9];
    const float* eW1     = (const float*)d_in[10];
    const float* eb1     = (const float*)d_in[11];
    const float* eW2     = (const float*)d_in[12];
    const float* eb2     = (const float*)d_in[13];
    const float* d0W     = (const float*)d_in[14];
    const float* d0b     = (const float*)d_in[15];
    const float* d1W     = (const float*)d_in[16];
    const float* d1b     = (const float*)d_in[17];
    const float* oW      = (const float*)d_in[18];
    const float* ob      = (const float*)d_in[19];
    float* out = (float*)d_out;

    // workspace layout (floats)
    float* ws   = (float*)d_ws;
    float* ctx  = ws;                                   // 16.78M  (also d1 output later)
    float* moe  = ws + 16777216;                        // 16.78M
    float* big  = ws + 2 * 16777216;                    // 33.55M: emb -> h_moe -> h0 (h0 spans into ybuf)
    float* ybuf = ws + 2 * 16777216 + 33554432;         // 33.55M: y slot0|slot1
    float* emb  = big;
    float* h0   = big;
    float* m1   = ctx;
    char* sm = (char*)(ws + 2 * 16777216 + 2 * 33554432);
    int*   e1          = (int*)sm;   sm += B_TOK * 4;
    int*   e2          = (int*)sm;   sm += B_TOK * 4;
    float* w1          = (float*)sm; sm += B_TOK * 4;
    float* w2          = (float*)sm; sm += B_TOK * 4;
    int*   keep        = (int*)sm;   sm += 2 * B_TOK * 4;
    int*   bh1         = (int*)sm;   sm += 64 * NEXP * 4;
    int*   bh2         = (int*)sm;   sm += 64 * NEXP * 4;
    int*   offs1       = (int*)sm;   sm += 64 * NEXP * 4;
    int*   offs2       = (int*)sm;   sm += 64 * NEXP * 4;
    int*   raw_total   = (int*)sm;   sm += 32 * 4;
    int*   ne          = (int*)sm;   sm += 32 * 4;
    int*   row_base    = (int*)sm;   sm += 32 * 4;
    float* psum_part   = (float*)sm; sm += (B_TOK / 4) * NEXP * 4;
    float* psum        = (float*)sm; sm += 32 * 4;
    int*   expert_rows = (int*)sm;   sm += NEXP * CAP * 4;

    // 1. context head
    hipLaunchKernelGGL(k_emb, dim3(B_TOK), dim3(256), 0, stream, deep_in, tab, emb);
    hipLaunchKernelGGL((gemm_plain<1>), dim3(DHALF / 64, B_TOK / 64), dim3(256), 0, stream,
                       emb, deep_W, deep_b, ctx, DMODEL, DMODEL, DHALF, DMODEL);
    hipLaunchKernelGGL(k_wide, dim3(B_TOK), dim3(256), 0, stream,
                       wide_in, wide_W, wide_b, gamma, beta, ctx);
    // 2. router + dispatch
    hipLaunchKernelGGL(k_router, dim3(B_TOK / 4), dim3(256), 0, stream,
                       ctx, rW, e1, e2, w1, w2, psum_part);
    hipLaunchKernelGGL(k_psum_reduce, dim3(NEXP), dim3(256), 0, stream, psum_part, psum);
    hipLaunchKernelGGL(k_hist, dim3(64), dim3(256), 0, stream, e1, e2, bh1, bh2);
    hipLaunchKernelGGL(k_scan, dim3(1), dim3(64), 0, stream,
                       bh1, bh2, offs1, offs2, raw_total, ne, row_base);
    hipLaunchKernelGGL(k_assign, dim3(64, 2), dim3(64), 0, stream,
                       e1, e2, offs1, offs2, expert_rows, keep);
    // 3. expert GEMMs (grouped, only real rows)
    hipLaunchKernelGGL((gemm_expert<1>), dim3(DMODEL / 64, CAP / 64, NEXP), dim3(256), 0, stream,
                       ctx, (const float*)nullptr, eW1, eb1, big, (float*)nullptr,
                       expert_rows, ne, row_base);
    hipLaunchKernelGGL((gemm_expert<2>), dim3(DMODEL / 64, CAP / 64, NEXP), dim3(256), 0, stream,
                       (const float*)nullptr, big, eW2, eb2, (float*)nullptr, ybuf,
                       expert_rows, ne, row_base);
    hipLaunchKernelGGL(k_combine, dim3(B_TOK), dim3(256), 0, stream, ybuf, keep, w1, w2, moe);
    // 4. final MLP
    hipLaunchKernelGGL((gemm_plain<1>), dim3(D3 / 64, B_TOK / 64), dim3(256), 0, stream,
                       moe, d0W, d0b, h0, DMODEL, DMODEL, D3, D3);
    hipLaunchKernelGGL((gemm_plain<1>), dim3(DMODEL / 64, B_TOK / 64), dim3(256), 0, stream,
                       h0, d1W, d1b, m1, D3, D3, DMODEL, DMODEL);
    hipLaunchKernelGGL(k_out, dim3(B_TOK), dim3(256), 0, stream, m1, oW, ob, out);
    hipLaunchKernelGGL(k_aux, dim3(1), dim3(64), 0, stream, raw_total, psum, out);
}